// Round 9
// baseline (87.218 us; speedup 1.0000x reference)
//
#include <hip/hip_runtime.h>
#include <hip/hip_fp16.h>

typedef _Float16 half8v __attribute__((ext_vector_type(8)));
typedef __fp16  pk16x2 __attribute__((ext_vector_type(2)));
typedef float f32x4 __attribute__((ext_vector_type(4)));

#define DEV __device__ __forceinline__
DEV float crelu(float x) { return fminf(fmaxf(x, -1.0f), 1.0f); }

DEV unsigned int pkrtz_u32(float a, float b) {
    pk16x2 p = __builtin_amdgcn_cvt_pkrtz(a, b);
    return __builtin_bit_cast(unsigned int, p);
}
DEV float lo2f(unsigned int w) { return __low2float(__builtin_bit_cast(__half2, w)); }
DEV float hi2f(unsigned int w) { return __high2float(__builtin_bit_cast(__half2, w)); }

// ---------------------------------------------------------------------------
// ws layout:
//   floats [0, 1152): w1t/w2t legacy + w3t [16][2] @ 1120 (win L3, s_load)
//   byte 19200 (float 4800): f16 MFMA B-frags: L1 [3][64][8], L2 [64][8]
//   float 8192:  e1q [74][16] float4: row c, lane j -> {E1[j][c], E1[16+j][c],
//                E1[32+(j&1)][c], 0}; row 72 = xl col; row 73 = bias e1
//   float 13312: e2q [35][16] float4 (row 34 = bias e2)
//   float 15872: e3q [16] float4 {E3[j], E3[16+j], j<2?E3[32+j]:0, 0}
//   byte 65536:  vbuf [B][36] half2 words (9.44 MB)
// ---------------------------------------------------------------------------
__global__ void prep_kernel(const float* __restrict__ W1, const float* __restrict__ W2,
                            const float* __restrict__ W3, const float* __restrict__ E1,
                            const float* __restrict__ E2, const float* __restrict__ e1b,
                            const float* __restrict__ e2b, const float* __restrict__ E3,
                            float* __restrict__ ws) {
    int t = threadIdx.x + blockIdx.x * blockDim.x;
    if (t < 864) {
        int s = t >> 4, o = t & 15;
        ws[t] = W1[o * 54 + s];
    } else if (t < 864 + 256) {
        int u = t - 864; int i = u >> 4, o = u & 15;
        ws[t] = W2[o * 16 + i];
    } else if (t < 1120 + 32) {
        int u = t - 1120; int i = u >> 1, o = u & 1;
        ws[t] = W3[o * 16 + i];
    } else if (t >= 8192 && t < 8192 + 1536) {
        // layer-1 B-frag
        _Float16* fr = (_Float16*)((char*)ws + 19200);
        int u = t - 8192;
        int ks = u >> 9, l = (u >> 3) & 63, j = u & 7;
        int n = l & 15;
        int kg = ks * 32 + ((l >> 4) << 3) + j;
        int ox = kg / 24, rem = kg - ox * 24, cy = rem >> 3, f = rem & 7;
        float v = (kg < 72 && f < 6) ? W1[n * 54 + ox * 18 + cy * 6 + f] : 0.0f;
        fr[u] = (_Float16)v;
    } else if (t >= 10240 && t < 10240 + 512) {
        // layer-2 B-frag
        _Float16* fr = (_Float16*)((char*)ws + 19200) + 1536;
        int u = t - 10240;
        int l = u >> 3, j = u & 7;
        int n = l & 15;
        int k = ((l >> 4) << 3) + j;
        float v = (k < 16) ? W2[n * 16 + k] : 0.0f;
        fr[u] = (_Float16)v;
    } else if (t >= 12288 && t < 12288 + 4736) {
        // e1q
        int u = t - 12288;
        int c = u >> 6, sl = u & 63, jj = sl >> 2, k = sl & 3;
        int o = (k == 0) ? jj : (k == 1) ? 16 + jj : 32 + (jj & 1);
        float v = 0.0f;
        if (k < 3) v = (c < 73) ? E1[o * 73 + c] : e1b[o];
        ws[8192 + u] = v;
    } else if (t >= 18432 && t < 18432 + 2240) {
        // e2q
        int u = t - 18432;
        int i = u >> 6, sl = u & 63, jj = sl >> 2, k = sl & 3;
        int o = (k == 0) ? jj : (k == 1) ? 16 + jj : 32 + (jj & 1);
        float v = 0.0f;
        if (k < 3) v = (i < 34) ? E2[o * 34 + i] : e2b[o];
        ws[13312 + u] = v;
    } else if (t >= 20992 && t < 20992 + 64) {
        // e3q
        int u = t - 20992;
        int jj = u >> 2, k = u & 3;
        float v = 0.0f;
        if (k == 0) v = E3[jj];
        else if (k == 1) v = E3[16 + jj];
        else if (k == 2) v = (jj < 2) ? E3[32 + jj] : 0.0f;
        ws[15872 + u] = v;
    }
}

// ---------------------------------------------------------------------------
// Phase 1 (MFMA): verbatim round-6 win_kernel (passed). One wave = 4 elements.
// ---------------------------------------------------------------------------
__global__ __launch_bounds__(256, 3) void win_kernel(
    const float* __restrict__ inp,
    const float* __restrict__ b1, const float* __restrict__ b2,
    const float* __restrict__ b3,
    const float* __restrict__ ws, const _Float16* __restrict__ frag,
    unsigned int* __restrict__ vout)
{
    __shared__ half8v lds[4 * 580];          // 37120 B per 4-wave block
    const int tid  = threadIdx.x;
    const int wid  = tid >> 6;
    const int lane = tid & 63;
    const int baseP = (blockIdx.x * 4 + wid) * 4;

    half8v* grid = lds + wid * 580;          // 288 half8
    half8v* h1   = grid + 288;               // 292 half8
    _Float16* h1h = (_Float16*)h1;

    const int r = lane & 15;
    const int g = lane >> 4;

    {
        const int es = lane >> 4, m = lane & 15;
        const float* __restrict__ src = inp + (size_t)(baseP + es) * 385 + 24 * m;
        #pragma unroll
        for (int c = 0; c < 4; ++c) {
            float f0 = src[c * 6 + 0], f1 = src[c * 6 + 1], f2 = src[c * 6 + 2];
            float f3 = src[c * 6 + 3], f4 = src[c * 6 + 4], f5 = src[c * 6 + 5];
            uint4 q;
            q.x = pkrtz_u32(f0, f1);
            q.y = pkrtz_u32(f2, f3);
            q.z = pkrtz_u32(f4, f5);
            q.w = q.z;
            *reinterpret_cast<uint4*>(grid + es * 72 + 4 * m + c) = q;
        }
    }

    const half8v* __restrict__ fr8 = (const half8v*)frag;
    half8v B1_0 = fr8[0 * 64 + lane];
    half8v B1_1 = fr8[1 * 64 + lane];
    half8v B1_2 = fr8[2 * 64 + lane];
    half8v B2f  = fr8[3 * 64 + lane];

    int off[3];
    #pragma unroll
    for (int ks = 0; ks < 3; ++ks) {
        int c = ks * 4 + g;
        int ox = c / 3, cy = c - 3 * ox;
        off[ks] = ox * 8 + cy;
    }

    const float bias1 = b1[r];
    const float bias2 = b2[r];
    const float* __restrict__ w3t = ws + 1120;
    const float b30 = b3[0], b31 = b3[1];

    int w = r, ebase = 0;
    #pragma unroll
    for (int t = 0; t < 9; ++t) {
        const int x = (w * 43) >> 8;
        const int y = w - x * 6;
        const int cellb = ebase + x * 8 + y;

        half8v a0 = grid[cellb + off[0]];
        half8v a1 = grid[cellb + off[1]];
        half8v a2 = grid[cellb + off[2]];

        f32x4 acc = {bias1, bias1, bias1, bias1};
        acc = __builtin_amdgcn_mfma_f32_16x16x32_f16(a0, B1_0, acc, 0, 0, 0);
        acc = __builtin_amdgcn_mfma_f32_16x16x32_f16(a1, B1_1, acc, 0, 0, 0);
        acc = __builtin_amdgcn_mfma_f32_16x16x32_f16(a2, B1_2, acc, 0, 0, 0);

        #pragma unroll
        for (int q = 0; q < 4; ++q)
            h1h[(t * 16 + g * 4 + q) * 16 + r] = (_Float16)crelu(acc[q]);

        half8v af = h1[(t * 16 + r) * 2 + g];
        f32x4 c2 = {bias2, bias2, bias2, bias2};
        c2 = __builtin_amdgcn_mfma_f32_16x16x32_f16(af, B2f, c2, 0, 0, 0);

        #pragma unroll
        for (int q = 0; q < 4; ++q)
            h1h[(t * 16 + g * 4 + q) * 16 + r] = (_Float16)crelu(c2[q]);

        w += 16;
        if (w >= 36) { w -= 36; ebase += 72; }
    }

    #pragma unroll
    for (int rep = 0; rep < 3; ++rep) {
        const int wg = lane + rep * 64;
        if (rep < 2 || lane < 16) {
            half8v ha = h1[wg * 2 + 0];
            half8v hb = h1[wg * 2 + 1];
            float v0 = b30, v1 = b31;
            #pragma unroll
            for (int i = 0; i < 8; ++i) {
                const float hv = (float)ha[i];
                v0 = fmaf(hv, w3t[i * 2 + 0], v0);
                v1 = fmaf(hv, w3t[i * 2 + 1], v1);
            }
            #pragma unroll
            for (int i = 0; i < 8; ++i) {
                const float hv = (float)hb[i];
                v0 = fmaf(hv, w3t[(8 + i) * 2 + 0], v0);
                v1 = fmaf(hv, w3t[(8 + i) * 2 + 1], v1);
            }
            vout[baseP * 36 + wg] = pkrtz_u32(crelu(v0), crelu(v1));
        }
    }
}

// ---------------------------------------------------------------------------
// Phase 2: 16 lanes per element, B*16 threads (16 waves/SIMD of TLP).
// Lane j owns head outputs {j, 16+j, 32+(j&1)}. NO LDS: vision from global
// vbuf (broadcast loads), h-exchange via __shfl broadcasts, butterfly reduce.
// ---------------------------------------------------------------------------
__global__ __launch_bounds__(256) void head2_kernel(
    const float* __restrict__ inp,
    const float* __restrict__ ws,
    const unsigned int* __restrict__ vbuf,
    const float* __restrict__ e3v,
    float* __restrict__ out)
{
    const int tid = threadIdx.x + blockIdx.x * 256;
    const int p = tid >> 4;                   // element
    const int j = tid & 15;                   // owner lane within 16-group
    const int lb = (threadIdx.x & 63) & 48;   // group base within the wave

    const float4* __restrict__ e1q = (const float4*)(ws + 8192);   // [74][16]
    const float4* __restrict__ e2q = (const float4*)(ws + 13312);  // [35][16]
    const float4* __restrict__ e3q = (const float4*)(ws + 15872);  // [16]

    const uint4* __restrict__ vp = (const uint4*)(vbuf + p * 36);

    // ---- E1: 72 vision cols + xl col + bias ----
    float4 bi = e1q[73 * 16 + j];
    float a0 = bi.x, a1s = bi.y, a2s = bi.z;
    #pragma unroll
    for (int q = 0; q < 9; ++q) {
        const uint4 qq = vp[q];
        float vv[8];
        vv[0] = lo2f(qq.x); vv[1] = hi2f(qq.x);
        vv[2] = lo2f(qq.y); vv[3] = hi2f(qq.y);
        vv[4] = lo2f(qq.z); vv[5] = hi2f(qq.z);
        vv[6] = lo2f(qq.w); vv[7] = hi2f(qq.w);
        #pragma unroll
        for (int u = 0; u < 8; ++u) {
            const float4 wv = e1q[(q * 8 + u) * 16 + j];
            a0  = fmaf(vv[u], wv.x, a0);
            a1s = fmaf(vv[u], wv.y, a1s);
            a2s = fmaf(vv[u], wv.z, a2s);
        }
    }
    {
        const float xv = inp[(size_t)p * 385 + 384];
        const float4 wv = e1q[72 * 16 + j];
        a0  = fmaf(xv, wv.x, a0);
        a1s = fmaf(xv, wv.y, a1s);
        a2s = fmaf(xv, wv.z, a2s);
    }
    const float h0 = crelu(a0), h1c = crelu(a1s), h2c = crelu(a2s);

    // ---- E2: h broadcast via shfl (no memory) ----
    const float4 b2q = e2q[34 * 16 + j];
    float c0 = b2q.x, c1 = b2q.y, c2a = b2q.z;
    #pragma unroll
    for (int i = 0; i < 16; ++i) {
        const float hv = __shfl(h0, lb + i);
        const float4 wv = e2q[i * 16 + j];
        c0  = fmaf(hv, wv.x, c0);
        c1  = fmaf(hv, wv.y, c1);
        c2a = fmaf(hv, wv.z, c2a);
    }
    #pragma unroll
    for (int i = 0; i < 16; ++i) {
        const float hv = __shfl(h1c, lb + i);
        const float4 wv = e2q[(16 + i) * 16 + j];
        c0  = fmaf(hv, wv.x, c0);
        c1  = fmaf(hv, wv.y, c1);
        c2a = fmaf(hv, wv.z, c2a);
    }
    {
        const float hv32 = __shfl(h2c, lb + 0);   // j=0 owns feature 32
        const float hv33 = __shfl(h2c, lb + 1);   // j=1 owns feature 33
        const float4 w32 = e2q[32 * 16 + j];
        const float4 w33 = e2q[33 * 16 + j];
        c0  = fmaf(hv32, w32.x, c0);  c0  = fmaf(hv33, w33.x, c0);
        c1  = fmaf(hv32, w32.y, c1);  c1  = fmaf(hv33, w33.y, c1);
        c2a = fmaf(hv32, w32.z, c2a); c2a = fmaf(hv33, w33.z, c2a);
    }

    // ---- E3 partial + 16-lane butterfly ----
    const float4 w3q = e3q[j];                // .z masked to lanes j<2
    float part = crelu(c0) * w3q.x + crelu(c1) * w3q.y + crelu(c2a) * w3q.z;
    part += __shfl_xor(part, 1);
    part += __shfl_xor(part, 2);
    part += __shfl_xor(part, 4);
    part += __shfl_xor(part, 8);
    if (j == 0) out[p] = crelu(part + e3v[0]);
}

extern "C" void kernel_launch(void* const* d_in, const int* in_sizes, int n_in,
                              void* d_out, int out_size, void* d_ws, size_t ws_size,
                              hipStream_t stream) {
    const float* inp = (const float*)d_in[0];
    const float* W1  = (const float*)d_in[1];
    const float* b1  = (const float*)d_in[2];
    const float* W2  = (const float*)d_in[3];
    const float* b2  = (const float*)d_in[4];
    const float* W3  = (const float*)d_in[5];
    const float* b3  = (const float*)d_in[6];
    const float* E1  = (const float*)d_in[7];
    const float* e1  = (const float*)d_in[8];
    const float* E2  = (const float*)d_in[9];
    const float* e2  = (const float*)d_in[10];
    const float* E3  = (const float*)d_in[11];
    const float* e3  = (const float*)d_in[12];
    float* out = (float*)d_out;
    float* ws  = (float*)d_ws;
    const _Float16* frag = (const _Float16*)((const char*)d_ws + 19200);
    unsigned int* vbuf = (unsigned int*)((char*)d_ws + 65536);

    prep_kernel<<<83, 256, 0, stream>>>(W1, W2, W3, E1, E2, e1, e2, E3, ws);

    const int B = 65536;
    win_kernel<<<B / 16, 256, 0, stream>>>(inp, b1, b2, b3, ws, frag, vbuf);
    head2_kernel<<<B * 16 / 256, 256, 0, stream>>>(inp, ws, vbuf, e3, out);
}

// Round 14
// 58.489 us; speedup vs baseline: 1.4912x; 1.4912x over previous
//
#include <hip/hip_runtime.h>
#include <hip/hip_fp16.h>

typedef _Float16 half8v __attribute__((ext_vector_type(8)));
typedef __fp16  pk16x2 __attribute__((ext_vector_type(2)));
typedef float f32x4 __attribute__((ext_vector_type(4)));

#define DEV __device__ __forceinline__
DEV float crelu(float x) { return fminf(fmaxf(x, -1.0f), 1.0f); }

DEV unsigned int pkrtz_u32(float a, float b) {
    pk16x2 p = __builtin_amdgcn_cvt_pkrtz(a, b);
    return __builtin_bit_cast(unsigned int, p);
}
DEV float lo2f(unsigned int w) { return __low2float(__builtin_bit_cast(__half2, w)); }
DEV float hi2f(unsigned int w) { return __high2float(__builtin_bit_cast(__half2, w)); }

DEV void lgkm0() { asm volatile("s_waitcnt lgkmcnt(0)" ::: "memory"); }

// ---------------------------------------------------------------------------
// ws layout (round-9/11):
//   floats [0, 1152): w1t/w2t legacy + w3t [16][2] @ 1120 (win L3, s_load)
//   byte 19200: f16 MFMA B-frags: L1 [3][64][8], L2 [64][8]
//   float 8192:  e1q [74][16] float4; float 13312: e2q [35][16] float4;
//   float 15872: e3q [16] float4
//   byte 65536:  vbuf [B][36] half2 words (9.44 MB)
// ---------------------------------------------------------------------------
__global__ void prep_kernel(const float* __restrict__ W1, const float* __restrict__ W2,
                            const float* __restrict__ W3, const float* __restrict__ E1,
                            const float* __restrict__ E2, const float* __restrict__ e1b,
                            const float* __restrict__ e2b, const float* __restrict__ E3,
                            float* __restrict__ ws) {
    int t = threadIdx.x + blockIdx.x * blockDim.x;
    if (t < 864) {
        int s = t >> 4, o = t & 15;
        ws[t] = W1[o * 54 + s];
    } else if (t < 864 + 256) {
        int u = t - 864; int i = u >> 4, o = u & 15;
        ws[t] = W2[o * 16 + i];
    } else if (t < 1120 + 32) {
        int u = t - 1120; int i = u >> 1, o = u & 1;
        ws[t] = W3[o * 16 + i];
    } else if (t >= 8192 && t < 8192 + 1536) {
        _Float16* fr = (_Float16*)((char*)ws + 19200);
        int u = t - 8192;
        int ks = u >> 9, l = (u >> 3) & 63, j = u & 7;
        int n = l & 15;
        int kg = ks * 32 + ((l >> 4) << 3) + j;
        int ox = kg / 24, rem = kg - ox * 24, cy = rem >> 3, f = rem & 7;
        float v = (kg < 72 && f < 6) ? W1[n * 54 + ox * 18 + cy * 6 + f] : 0.0f;
        fr[u] = (_Float16)v;
    } else if (t >= 10240 && t < 10240 + 512) {
        _Float16* fr = (_Float16*)((char*)ws + 19200) + 1536;
        int u = t - 10240;
        int l = u >> 3, j = u & 7;
        int n = l & 15;
        int k = ((l >> 4) << 3) + j;
        float v = (k < 16) ? W2[n * 16 + k] : 0.0f;
        fr[u] = (_Float16)v;
    } else if (t >= 12288 && t < 12288 + 4736) {
        int u = t - 12288;
        int c = u >> 6, sl = u & 63, jj = sl >> 2, k = sl & 3;
        int o = (k == 0) ? jj : (k == 1) ? 16 + jj : 32 + (jj & 1);
        float v = 0.0f;
        if (k < 3) v = (c < 73) ? E1[o * 73 + c] : e1b[o];
        ws[8192 + u] = v;
    } else if (t >= 18432 && t < 18432 + 2240) {
        int u = t - 18432;
        int i = u >> 6, sl = u & 63, jj = sl >> 2, k = sl & 3;
        int o = (k == 0) ? jj : (k == 1) ? 16 + jj : 32 + (jj & 1);
        float v = 0.0f;
        if (k < 3) v = (i < 34) ? E2[o * 34 + i] : e2b[o];
        ws[13312 + u] = v;
    } else if (t >= 20992 && t < 20992 + 64) {
        int u = t - 20992;
        int jj = u >> 2, k = u & 3;
        float v = 0.0f;
        if (k == 0) v = E3[jj];
        else if (k == 1) v = E3[16 + jj];
        else if (k == 2) v = (jj < 2) ? E3[32 + jj] : 0.0f;
        ws[15872 + u] = v;
    }
}

// ---------------------------------------------------------------------------
// Phase 1 (MFMA): one wave = 4 elements. NEW: the wave's LDS region is
// ZERO-INITIALIZED first. The K-pad scheme reads "garbage" LDS cells under
// zero B-weights; if stale LDS bits decode as f16 Inf/NaN then 0*Inf=NaN
// poisons the accumulator (crelu(NaN)=-1 -> absmax 2.0, nondeterministic
// across runs). Zeroing makes every pad read 0*0=0, deterministic.
// ---------------------------------------------------------------------------
__global__ __launch_bounds__(256, 3) void win_kernel(
    const float* __restrict__ inp,
    const float* __restrict__ b1, const float* __restrict__ b2,
    const float* __restrict__ b3,
    const float* __restrict__ ws, const _Float16* __restrict__ frag,
    unsigned int* __restrict__ vout)
{
    __shared__ half8v lds[4 * 580];
    const int tid  = threadIdx.x;
    const int wid  = tid >> 6;
    const int lane = tid & 63;
    const int baseP = (blockIdx.x * 4 + wid) * 4;

    half8v* grid = lds + wid * 580;
    half8v* h1   = grid + 288;
    _Float16* h1h = (_Float16*)h1;

    const int r = lane & 15;
    const int g = lane >> 4;

    // ---- zero the wave's whole LDS region (580 half8s) ----
    {
        const uint4 z = {0u, 0u, 0u, 0u};
        #pragma unroll
        for (int i = 0; i < 10; ++i) {
            const int idx = lane + i * 64;
            if (i < 9 || idx < 580)
                *reinterpret_cast<uint4*>(grid + idx) = z;
        }
    }
    lgkm0();

    // ---- stage 4 elements' grids ----
    {
        const int es = lane >> 4, m = lane & 15;
        const float* __restrict__ src = inp + (size_t)(baseP + es) * 385 + 24 * m;
        #pragma unroll
        for (int c = 0; c < 4; ++c) {
            float f0 = src[c * 6 + 0], f1 = src[c * 6 + 1], f2 = src[c * 6 + 2];
            float f3 = src[c * 6 + 3], f4 = src[c * 6 + 4], f5 = src[c * 6 + 5];
            uint4 q;
            q.x = pkrtz_u32(f0, f1);
            q.y = pkrtz_u32(f2, f3);
            q.z = pkrtz_u32(f4, f5);
            q.w = q.z;
            *reinterpret_cast<uint4*>(grid + es * 72 + 4 * m + c) = q;
        }
    }
    lgkm0();                                  // grid writes -> cross-lane reads

    const half8v* __restrict__ fr8 = (const half8v*)frag;
    half8v B1_0 = fr8[0 * 64 + lane];
    half8v B1_1 = fr8[1 * 64 + lane];
    half8v B1_2 = fr8[2 * 64 + lane];
    half8v B2f  = fr8[3 * 64 + lane];

    int off[3];
    #pragma unroll
    for (int ks = 0; ks < 3; ++ks) {
        int c = ks * 4 + g;
        int ox = c / 3, cy = c - 3 * ox;
        off[ks] = ox * 8 + cy;
    }

    const float bias1 = b1[r];
    const float bias2 = b2[r];
    const float* __restrict__ w3t = ws + 1120;
    const float b30 = b3[0], b31 = b3[1];

    int w = r, ebase = 0;
    #pragma unroll
    for (int t = 0; t < 9; ++t) {
        const int x = (w * 43) >> 8;
        const int y = w - x * 6;
        const int cellb = ebase + x * 8 + y;

        half8v a0 = grid[cellb + off[0]];
        half8v a1 = grid[cellb + off[1]];
        half8v a2 = grid[cellb + off[2]];

        f32x4 acc = {bias1, bias1, bias1, bias1};
        acc = __builtin_amdgcn_mfma_f32_16x16x32_f16(a0, B1_0, acc, 0, 0, 0);
        acc = __builtin_amdgcn_mfma_f32_16x16x32_f16(a1, B1_1, acc, 0, 0, 0);
        acc = __builtin_amdgcn_mfma_f32_16x16x32_f16(a2, B1_2, acc, 0, 0, 0);

        #pragma unroll
        for (int q = 0; q < 4; ++q)
            h1h[(t * 16 + g * 4 + q) * 16 + r] = (_Float16)crelu(acc[q]);
        lgkm0();                              // h1 writes -> af read

        half8v af = h1[(t * 16 + r) * 2 + g];
        f32x4 c2 = {bias2, bias2, bias2, bias2};
        c2 = __builtin_amdgcn_mfma_f32_16x16x32_f16(af, B2f, c2, 0, 0, 0);

        #pragma unroll
        for (int q = 0; q < 4; ++q)
            h1h[(t * 16 + g * 4 + q) * 16 + r] = (_Float16)crelu(c2[q]);

        w += 16;
        if (w >= 36) { w -= 36; ebase += 72; }
    }
    lgkm0();                                  // h2 writes -> L3 reads

    #pragma unroll
    for (int rep = 0; rep < 3; ++rep) {
        const int wg = lane + rep * 64;
        if (rep < 2 || lane < 16) {
            half8v ha = h1[wg * 2 + 0];
            half8v hb = h1[wg * 2 + 1];
            float v0 = b30, v1 = b31;
            #pragma unroll
            for (int i = 0; i < 8; ++i) {
                const float hv = (float)ha[i];
                v0 = fmaf(hv, w3t[i * 2 + 0], v0);
                v1 = fmaf(hv, w3t[i * 2 + 1], v1);
            }
            #pragma unroll
            for (int i = 0; i < 8; ++i) {
                const float hv = (float)hb[i];
                v0 = fmaf(hv, w3t[(8 + i) * 2 + 0], v0);
                v1 = fmaf(hv, w3t[(8 + i) * 2 + 1], v1);
            }
            vout[baseP * 36 + wg] = pkrtz_u32(crelu(v0), crelu(v1));
        }
    }
}

// ---------------------------------------------------------------------------
// Phase 2 (round-11 head2b): 16-lane group processes FOUR elements, weights
// amortized 4x, NO LDS, h-exchange via __shfl, butterfly reduce.
// ---------------------------------------------------------------------------
__global__ __launch_bounds__(256) void head2b_kernel(
    const float* __restrict__ inp,
    const float* __restrict__ ws,
    const unsigned int* __restrict__ vbuf,
    const float* __restrict__ e3v,
    float* __restrict__ out)
{
    const int tid = threadIdx.x + blockIdx.x * 256;
    const int G = tid >> 4;
    const int j = tid & 15;
    const int lb = (threadIdx.x & 63) & 48;
    const int p0 = G * 4;

    const float4* __restrict__ e1q = (const float4*)(ws + 8192);
    const float4* __restrict__ e2q = (const float4*)(ws + 13312);
    const float4* __restrict__ e3q = (const float4*)(ws + 15872);

    float4 bi = e1q[73 * 16 + j];
    float a0[4], a1s[4], a2s[4];
    #pragma unroll
    for (int e = 0; e < 4; ++e) { a0[e] = bi.x; a1s[e] = bi.y; a2s[e] = bi.z; }

    #pragma unroll
    for (int q = 0; q < 9; ++q) {
        uint4 qq[4];
        #pragma unroll
        for (int e = 0; e < 4; ++e)
            qq[e] = *(const uint4*)(vbuf + (size_t)(p0 + e) * 36 + q * 4);
        float vv[4][8];
        #pragma unroll
        for (int e = 0; e < 4; ++e) {
            vv[e][0] = lo2f(qq[e].x); vv[e][1] = hi2f(qq[e].x);
            vv[e][2] = lo2f(qq[e].y); vv[e][3] = hi2f(qq[e].y);
            vv[e][4] = lo2f(qq[e].z); vv[e][5] = hi2f(qq[e].z);
            vv[e][6] = lo2f(qq[e].w); vv[e][7] = hi2f(qq[e].w);
        }
        #pragma unroll
        for (int u = 0; u < 8; ++u) {
            const float4 wv = e1q[(q * 8 + u) * 16 + j];
            #pragma unroll
            for (int e = 0; e < 4; ++e) {
                a0[e]  = fmaf(vv[e][u], wv.x, a0[e]);
                a1s[e] = fmaf(vv[e][u], wv.y, a1s[e]);
                a2s[e] = fmaf(vv[e][u], wv.z, a2s[e]);
            }
        }
    }
    {
        const float4 wv = e1q[72 * 16 + j];
        #pragma unroll
        for (int e = 0; e < 4; ++e) {
            const float xv = inp[(size_t)(p0 + e) * 385 + 384];
            a0[e]  = fmaf(xv, wv.x, a0[e]);
            a1s[e] = fmaf(xv, wv.y, a1s[e]);
            a2s[e] = fmaf(xv, wv.z, a2s[e]);
        }
    }
    float h0[4], h1c[4], h2c[4];
    #pragma unroll
    for (int e = 0; e < 4; ++e) {
        h0[e]  = crelu(a0[e]);
        h1c[e] = crelu(a1s[e]);
        h2c[e] = crelu(a2s[e]);
    }

    const float4 b2q = e2q[34 * 16 + j];
    float c0[4], c1[4], c2a[4];
    #pragma unroll
    for (int e = 0; e < 4; ++e) { c0[e] = b2q.x; c1[e] = b2q.y; c2a[e] = b2q.z; }

    #pragma unroll
    for (int i = 0; i < 16; ++i) {
        const float4 wv = e2q[i * 16 + j];
        #pragma unroll
        for (int e = 0; e < 4; ++e) {
            const float hv = __shfl(h0[e], lb + i);
            c0[e]  = fmaf(hv, wv.x, c0[e]);
            c1[e]  = fmaf(hv, wv.y, c1[e]);
            c2a[e] = fmaf(hv, wv.z, c2a[e]);
        }
    }
    #pragma unroll
    for (int i = 0; i < 16; ++i) {
        const float4 wv = e2q[(16 + i) * 16 + j];
        #pragma unroll
        for (int e = 0; e < 4; ++e) {
            const float hv = __shfl(h1c[e], lb + i);
            c0[e]  = fmaf(hv, wv.x, c0[e]);
            c1[e]  = fmaf(hv, wv.y, c1[e]);
            c2a[e] = fmaf(hv, wv.z, c2a[e]);
        }
    }
    {
        const float4 w32 = e2q[32 * 16 + j];
        const float4 w33 = e2q[33 * 16 + j];
        #pragma unroll
        for (int e = 0; e < 4; ++e) {
            const float hv32 = __shfl(h2c[e], lb + 0);
            const float hv33 = __shfl(h2c[e], lb + 1);
            c0[e]  = fmaf(hv32, w32.x, c0[e]);  c0[e]  = fmaf(hv33, w33.x, c0[e]);
            c1[e]  = fmaf(hv32, w32.y, c1[e]);  c1[e]  = fmaf(hv33, w33.y, c1[e]);
            c2a[e] = fmaf(hv32, w32.z, c2a[e]); c2a[e] = fmaf(hv33, w33.z, c2a[e]);
        }
    }

    const float4 w3q = e3q[j];
    const float e3b = e3v[0];
    float s[4];
    #pragma unroll
    for (int e = 0; e < 4; ++e) {
        float part = crelu(c0[e]) * w3q.x + crelu(c1[e]) * w3q.y
                   + crelu(c2a[e]) * w3q.z;
        part += __shfl_xor(part, 1);
        part += __shfl_xor(part, 2);
        part += __shfl_xor(part, 4);
        part += __shfl_xor(part, 8);
        s[e] = crelu(part + e3b);
    }
    if (j == 0) {
        float4 o4 = {s[0], s[1], s[2], s[3]};
        *reinterpret_cast<float4*>(out + p0) = o4;
    }
}

extern "C" void kernel_launch(void* const* d_in, const int* in_sizes, int n_in,
                              void* d_out, int out_size, void* d_ws, size_t ws_size,
                              hipStream_t stream) {
    const float* inp = (const float*)d_in[0];
    const float* W1  = (const float*)d_in[1];
    const float* b1  = (const float*)d_in[2];
    const float* W2  = (const float*)d_in[3];
    const float* b2  = (const float*)d_in[4];
    const float* W3  = (const float*)d_in[5];
    const float* b3  = (const float*)d_in[6];
    const float* E1  = (const float*)d_in[7];
    const float* e1  = (const float*)d_in[8];
    const float* E2  = (const float*)d_in[9];
    const float* e2  = (const float*)d_in[10];
    const float* E3  = (const float*)d_in[11];
    const float* e3  = (const float*)d_in[12];
    float* out = (float*)d_out;
    float* ws  = (float*)d_ws;
    const _Float16* frag = (const _Float16*)((const char*)d_ws + 19200);
    unsigned int* vbuf = (unsigned int*)((char*)d_ws + 65536);

    prep_kernel<<<83, 256, 0, stream>>>(W1, W2, W3, E1, E2, e1, e2, E3, ws);

    const int B = 65536;
    win_kernel<<<B / 16, 256, 0, stream>>>(inp, b1, b2, b3, ws, frag, vbuf);
    head2b_kernel<<<B * 4 / 256, 256, 0, stream>>>(inp, ws, vbuf, e3, out);
}